// Round 18
// baseline (135.095 us; speedup 1.0000x reference)
//
#include <hip/hip_runtime.h>
#include <math.h>

constexpr int BB = 2, NN = 4096, MM = 16384;
constexpr int CSL = 8;                   // col-pass slices over N (512 sampled each)
constexpr int RSL = 32;                  // row-pass slices over M (512 raw each)
constexpr int REP = 8;                   // DIAGNOSTIC: repeat stream loop 8x (idempotent min)
constexpr unsigned INFBITS = 0x7F800000u;
constexpr ushort ONEB = 0x3F80;          // bf16 1.0

typedef __attribute__((ext_vector_type(8)))  short  short8;
typedef __attribute__((ext_vector_type(8)))  ushort ushort8;
typedef __attribute__((ext_vector_type(16))) float  f32x16;

// R18 = R17 with pair split into two NAMED kernels, each repeating its stream
// loop REP times (bit-identical result: min is idempotent; opaque z breaks
// CSE so the hardware really re-executes loads+MFMAs). Purpose: lift the hot
// loop above the 40us fill-kernel floor in the rocprof top-5 so we finally
// see its dur/VGPR/VALUBusy/MfmaUtil/FETCH and identify the ~30us stall.
__device__ __forceinline__ ushort f2bf(float f) {
    unsigned u = __float_as_uint(f);
    u += 0x7FFF + ((u >> 16) & 1);
    return (ushort)(u >> 16);
}
__device__ __forceinline__ void split2(float v, ushort& h, ushort& l) {
    h = f2bf(v);
    l = f2bf(v - __uint_as_float(((unsigned)h) << 16));
}
__device__ __forceinline__ float vmin16(const f32x16& c) {
    float a0 = fminf(fminf(c[0], c[1]),   fminf(c[2], c[3]));
    float a1 = fminf(fminf(c[4], c[5]),   fminf(c[6], c[7]));
    float a2 = fminf(fminf(c[8], c[9]),   fminf(c[10], c[11]));
    float a3 = fminf(fminf(c[12], c[13]), fminf(c[14], c[15]));
    return fminf(fminf(a0, a1), fminf(a2, a3));
}
__device__ __forceinline__ short8 bfrag(float4 v, int half) {
    float n = fmaf(v.z, v.z, fmaf(v.y, v.y, v.x * v.x));
    ushort hx,lx,hy,ly,hz,lz,hn,ln;
    split2(v.x, hx, lx); split2(v.y, hy, ly);
    split2(v.z, hz, lz); split2(n, hn, ln);
    ushort8 w0 = ushort8{hx,hy,hz,lx,ly,lz,hx,hy};
    ushort8 w1 = ushort8{hz,ONEB,ONEB,hn,ln,0,0,0};
    ushort8 sel = half ? w1 : w0;
    return *(short8*)&sel;
}

__global__ __launch_bounds__(256) void pack_kernel(
    const float* __restrict__ sampled, const float* __restrict__ raw,
    ushort* __restrict__ As, ushort* __restrict__ Ar,
    unsigned* __restrict__ counter)
{
    const int g = blockIdx.x * 256 + threadIdx.x;   // 0 .. BB*(NN+MM)-1
    if (g == 0) *counter = 0u;
    float4 v;
    ushort* dst;
    if (g < BB * NN) {
        v = ((const float4*)sampled)[g];
        dst = As + ((size_t)(g >> 5) << 9) + (g & 31) * 8;
    } else {
        const int p = g - BB * NN;
        v = ((const float4*)raw)[p];
        dst = Ar + ((size_t)(p >> 5) << 9) + (p & 31) * 8;
    }
    float n = fmaf(v.z, v.z, fmaf(v.y, v.y, v.x * v.x));
    ushort hx,lx,hy,ly,hz,lz,hn,ln;
    split2(-2.f * v.x, hx, lx); split2(-2.f * v.y, hy, ly);
    split2(-2.f * v.z, hz, lz); split2(n, hn, ln);
    *(ushort8*)(dst)       = ushort8{hx,hy,hz,hx,hy,hz,lx,ly};   // K 0-7
    *(ushort8*)(dst + 256) = ushort8{lz,hn,ln,ONEB,ONEB,0,0,0};  // K 8-15
}

// wave owns 128 pts (4 B-frags), streams 16 packed A-tiles, REP passes.
__device__ __forceinline__ void pair_body(
    const float4* ownp, const ushort* Ap, float* outp, int lane, int half)
{
    const float INF = __uint_as_float(INFBITS);
    const f32x16 zero = {0.f,0.f,0.f,0.f,0.f,0.f,0.f,0.f,
                         0.f,0.f,0.f,0.f,0.f,0.f,0.f,0.f};
    const int l31 = lane & 31;
    short8 bfr0 = bfrag(ownp[l31],      half);
    short8 bfr1 = bfrag(ownp[32 + l31], half);
    short8 bfr2 = bfrag(ownp[64 + l31], half);
    short8 bfr3 = bfrag(ownp[96 + l31], half);

    unsigned z;
    asm volatile("s_mov_b32 %0, 0" : "=s"(z));   // opaque 0: defeats CSE across reps

    float acc0 = INF, acc1 = INF, acc2 = INF, acc3 = INF;
#pragma unroll 1
    for (int rep = 0; rep < REP; ++rep) {
#pragma unroll 1
        for (int t = 0; t < 16; ++t) {
            const int tt = t ^ (int)z;           // == t at runtime
            short8 af = *(const short8*)(Ap + ((size_t)tt << 9));
            f32x16 c0 = __builtin_amdgcn_mfma_f32_32x32x16_bf16(af, bfr0, zero, 0, 0, 0);
            acc0 = fminf(acc0, vmin16(c0));
            f32x16 c1 = __builtin_amdgcn_mfma_f32_32x32x16_bf16(af, bfr1, zero, 0, 0, 0);
            acc1 = fminf(acc1, vmin16(c1));
            f32x16 c2 = __builtin_amdgcn_mfma_f32_32x32x16_bf16(af, bfr2, zero, 0, 0, 0);
            acc2 = fminf(acc2, vmin16(c2));
            f32x16 c3 = __builtin_amdgcn_mfma_f32_32x32x16_bf16(af, bfr3, zero, 0, 0, 0);
            acc3 = fminf(acc3, vmin16(c3));
        }
    }
    acc0 = fminf(acc0, __shfl_xor(acc0, 32, 64));
    acc1 = fminf(acc1, __shfl_xor(acc1, 32, 64));
    acc2 = fminf(acc2, __shfl_xor(acc2, 32, 64));
    acc3 = fminf(acc3, __shfl_xor(acc3, 32, 64));
    if (lane < 32) {
        outp[lane]      = fmaxf(acc0, 0.f);
        outp[32 + lane] = fmaxf(acc1, 0.f);
        outp[64 + lane] = fmaxf(acc2, 0.f);
        outp[96 + lane] = fmaxf(acc3, 0.f);
    }
}

__global__ __launch_bounds__(256, 4) void pair_col_kernel(
    const float* __restrict__ raw, const ushort* __restrict__ As,
    float* __restrict__ colpart)
{
    const int tid = threadIdx.x, w = tid >> 6, lane = tid & 63, half = lane >> 5;
    int idx = blockIdx.x;                        // [0,512)
    const int b = idx >> 8; idx &= 255;
    const int ob = idx & 31, sl = idx >> 5;      // ob:[0,32) sl:[0,8)
    const int own0 = ob * 512 + w * 128;
    const float4* ownp = (const float4*)raw + (size_t)b * MM + own0;
    const ushort* Ap = As + (((size_t)(b * (NN / 32) + sl * 16)) << 9) + lane * 8;
    float* outp = colpart + ((size_t)sl * BB + b) * MM + own0;
    pair_body(ownp, Ap, outp, lane, half);
}

__global__ __launch_bounds__(256, 4) void pair_row_kernel(
    const float* __restrict__ sampled, const ushort* __restrict__ Ar,
    float* __restrict__ rowpart)
{
    const int tid = threadIdx.x, w = tid >> 6, lane = tid & 63, half = lane >> 5;
    int idx = blockIdx.x;                        // [0,512)
    const int b = idx >> 8; idx &= 255;
    const int ob = idx & 7, sl = idx >> 3;       // ob:[0,8) sl:[0,32)
    const int own0 = ob * 512 + w * 128;
    const float4* ownp = (const float4*)sampled + (size_t)b * NN + own0;
    const ushort* Ap = Ar + (((size_t)(b * (MM / 32) + sl * 16)) << 9) + lane * 8;
    float* outp = rowpart + ((size_t)sl * BB + b) * NN + own0;
    pair_body(ownp, Ap, outp, lane, half);
}

__global__ __launch_bounds__(256) void reduce_kernel(
    const float* __restrict__ rowpart,
    const float* __restrict__ colpart,
    float* __restrict__ part,            // [128][3]
    unsigned* __restrict__ counter,
    float* __restrict__ out)
{
    const int k = blockIdx.x, b = k >> 6, s = k & 63;
    const int tid = threadIdx.x;
    const float INF = __uint_as_float(INFBITS);

    const int col = s * 256 + tid;
    float v = INF;
#pragma unroll
    for (int sl = 0; sl < CSL; ++sl)
        v = fminf(v, colpart[((size_t)sl * BB + b) * MM + col]);
    float sB = sqrtf(v);

    const int row = s * 64 + (tid & 63);
    const int jq  = tid >> 6;
    float wv2 = INF;
#pragma unroll
    for (int q = 0; q < RSL / 4; ++q)
        wv2 = fminf(wv2, rowpart[((size_t)(jq * (RSL / 4) + q) * BB + b) * NN + row]);
    __shared__ float rred[4][64];
    rred[jq][tid & 63] = wv2;
    __syncthreads();
    float sF = 0.f, mF = 0.f;
    if (tid < 64) {
        float rmn = fminf(fminf(rred[0][tid], rred[1][tid]),
                          fminf(rred[2][tid], rred[3][tid]));
        float d = sqrtf(rmn);
        sF = d; mF = d;
    }

    for (int m = 1; m < 64; m <<= 1) {
        sB += __shfl_xor(sB, m, 64);
        sF += __shfl_xor(sF, m, 64);
        mF = fmaxf(mF, __shfl_xor(mF, m, 64));
    }
    __shared__ float red[3][4];
    const int lane = tid & 63, wvi = tid >> 6;
    if (lane == 0) { red[0][wvi] = sB; red[1][wvi] = sF; red[2][wvi] = mF; }
    __syncthreads();

    __shared__ bool isLast;
    if (tid == 0) {
        part[k * 3 + 0] = red[0][0] + red[0][1] + red[0][2] + red[0][3];
        part[k * 3 + 1] = red[1][0] + red[1][1] + red[1][2] + red[1][3];
        part[k * 3 + 2] = fmaxf(fmaxf(red[2][0], red[2][1]),
                                fmaxf(red[2][2], red[2][3]));
        __threadfence();
        isLast = (atomicAdd(counter, 1u) == 127u);
    }
    __syncthreads();
    if (!isLast) return;

    __threadfence();
    volatile const float* vp = part;
    float fB = 0.f, fF = 0.f, fM = 0.f;
    if (tid < 128) {
        fB = vp[tid * 3 + 0]; fF = vp[tid * 3 + 1]; fM = vp[tid * 3 + 2];
    }
    for (int m = 1; m < 64; m <<= 1) {
        fB += __shfl_xor(fB, m, 64);
        fF += __shfl_xor(fF, m, 64);
        fM = fmaxf(fM, __shfl_xor(fM, m, 64));
    }
    __shared__ float fin[2][3];
    if (tid < 128 && (tid & 63) == 0) {
        fin[tid >> 6][0] = fB; fin[tid >> 6][1] = fF; fin[tid >> 6][2] = fM;
    }
    __syncthreads();
    if (tid == 0) {
        float l0 = 5.f * fin[0][0] / (float)MM + fin[0][1] / (float)NN + fin[0][2];
        float l1 = 5.f * fin[1][0] / (float)MM + fin[1][1] / (float)NN + fin[1][2];
        *out = 0.5f * (l0 + l1);
    }
}

extern "C" void kernel_launch(void* const* d_in, const int* in_sizes, int n_in,
                              void* d_out, int out_size, void* d_ws, size_t ws_size,
                              hipStream_t stream) {
    const float* sampled = (const float*)d_in[0];
    const float* raw     = (const float*)d_in[1];
    ushort* As     = (ushort*)d_ws;                          // BB*NN*32B = 256 KB
    ushort* Ar     = As + (size_t)BB * NN * 16;              // BB*MM*32B = 1 MB
    float* colpart = (float*)(Ar + (size_t)BB * MM * 16);    // CSL*BB*MM = 1 MB
    float* rowpart = colpart + (size_t)CSL * BB * MM;        // RSL*BB*NN = 1 MB
    float* part    = rowpart + (size_t)RSL * BB * NN;
    unsigned* counter = (unsigned*)(part + 3 * 128);
    float* out     = (float*)d_out;

    pack_kernel<<<(BB * (NN + MM)) / 256, 256, 0, stream>>>(sampled, raw, As, Ar, counter);
    pair_col_kernel<<<512, 256, 0, stream>>>(raw, As, colpart);
    pair_row_kernel<<<512, 256, 0, stream>>>(sampled, Ar, rowpart);
    reduce_kernel<<<128, 256, 0, stream>>>(rowpart, colpart, part, counter, out);
}

// Round 19
// 34.865 us; speedup vs baseline: 3.8748x; 3.8748x over previous
//
#include <hip/hip_runtime.h>
#include <math.h>

constexpr int BB = 2, NN = 4096, MM = 16384;
constexpr int CSL = 16;                  // col-pass slices over N (256 sampled each)
constexpr int RSL = 64;                  // row-pass slices over M (256 raw each)
constexpr int NT  = 8;                   // stream tiles per slice (8 x 32 pts)
constexpr unsigned INFBITS = 0x7F800000u;
constexpr ushort ONEB = 0x3F80;          // bf16 1.0

typedef __attribute__((ext_vector_type(8)))  short  short8;
typedef __attribute__((ext_vector_type(8)))  ushort ushort8;
typedef __attribute__((ext_vector_type(16))) float  f32x16;

// R19 = R18 structure (split passes - measured 8.7us/pass vs fused ~27us) with:
//  REP=1; min3-fused reduce tree (8 v_min3 per MFMA instead of 16 v_min -
//  VALUBusy was 60% vs MfmaUtil 19%: VALU is the pipe to cut); grid x2 per
//  pass (1024 blocks = 4/CU; occupancy was 17.5%, grid-capped at 2 blocks/CU).
__device__ __forceinline__ ushort f2bf(float f) {
    unsigned u = __float_as_uint(f);
    u += 0x7FFF + ((u >> 16) & 1);
    return (ushort)(u >> 16);
}
__device__ __forceinline__ void split2(float v, ushort& h, ushort& l) {
    h = f2bf(v);
    l = f2bf(v - __uint_as_float(((unsigned)h) << 16));
}
__device__ __forceinline__ float min3f(float a, float b, float c) {
    return fminf(fminf(a, b), c);        // fuses to v_min3_f32 (T17)
}
// 16 C-values + running acc -> new acc: 8 min3 ops, depth 3
__device__ __forceinline__ float accmin16(float acc, const f32x16& c) {
    float a = min3f(c[0],  c[1],  c[2]);
    float b = min3f(c[3],  c[4],  c[5]);
    float d = min3f(c[6],  c[7],  c[8]);
    float e = min3f(c[9],  c[10], c[11]);
    float f = min3f(c[12], c[13], c[14]);
    float g = min3f(a, b, d);
    float h = min3f(e, f, c[15]);
    return min3f(acc, g, h);
}
__device__ __forceinline__ short8 bfrag(float4 v, int half) {
    float n = fmaf(v.z, v.z, fmaf(v.y, v.y, v.x * v.x));
    ushort hx,lx,hy,ly,hz,lz,hn,ln;
    split2(v.x, hx, lx); split2(v.y, hy, ly);
    split2(v.z, hz, lz); split2(n, hn, ln);
    ushort8 w0 = ushort8{hx,hy,hz,lx,ly,lz,hx,hy};
    ushort8 w1 = ushort8{hz,ONEB,ONEB,hn,ln,0,0,0};
    ushort8 sel = half ? w1 : w0;
    return *(short8*)&sel;
}

__global__ __launch_bounds__(256) void pack_kernel(
    const float* __restrict__ sampled, const float* __restrict__ raw,
    ushort* __restrict__ As, ushort* __restrict__ Ar,
    unsigned* __restrict__ counter)
{
    const int g = blockIdx.x * 256 + threadIdx.x;   // 0 .. BB*(NN+MM)-1
    if (g == 0) *counter = 0u;
    float4 v;
    ushort* dst;
    if (g < BB * NN) {
        v = ((const float4*)sampled)[g];
        dst = As + ((size_t)(g >> 5) << 9) + (g & 31) * 8;
    } else {
        const int p = g - BB * NN;
        v = ((const float4*)raw)[p];
        dst = Ar + ((size_t)(p >> 5) << 9) + (p & 31) * 8;
    }
    float n = fmaf(v.z, v.z, fmaf(v.y, v.y, v.x * v.x));
    ushort hx,lx,hy,ly,hz,lz,hn,ln;
    split2(-2.f * v.x, hx, lx); split2(-2.f * v.y, hy, ly);
    split2(-2.f * v.z, hz, lz); split2(n, hn, ln);
    *(ushort8*)(dst)       = ushort8{hx,hy,hz,hx,hy,hz,lx,ly};   // K 0-7
    *(ushort8*)(dst + 256) = ushort8{lz,hn,ln,ONEB,ONEB,0,0,0};  // K 8-15
}

// wave owns 128 pts (4 B-frags); streams NT packed A-tiles.
__device__ __forceinline__ void pair_body(
    const float4* ownp, const ushort* Ap, float* outp, int lane, int half)
{
    const float INF = __uint_as_float(INFBITS);
    const f32x16 zero = {0.f,0.f,0.f,0.f,0.f,0.f,0.f,0.f,
                         0.f,0.f,0.f,0.f,0.f,0.f,0.f,0.f};
    const int l31 = lane & 31;
    short8 bfr0 = bfrag(ownp[l31],      half);
    short8 bfr1 = bfrag(ownp[32 + l31], half);
    short8 bfr2 = bfrag(ownp[64 + l31], half);
    short8 bfr3 = bfrag(ownp[96 + l31], half);

    float acc0 = INF, acc1 = INF, acc2 = INF, acc3 = INF;
#pragma unroll 2
    for (int t = 0; t < NT; ++t) {
        short8 af = *(const short8*)(Ap + ((size_t)t << 9));
        f32x16 c0 = __builtin_amdgcn_mfma_f32_32x32x16_bf16(af, bfr0, zero, 0, 0, 0);
        acc0 = accmin16(acc0, c0);
        f32x16 c1 = __builtin_amdgcn_mfma_f32_32x32x16_bf16(af, bfr1, zero, 0, 0, 0);
        acc1 = accmin16(acc1, c1);
        f32x16 c2 = __builtin_amdgcn_mfma_f32_32x32x16_bf16(af, bfr2, zero, 0, 0, 0);
        acc2 = accmin16(acc2, c2);
        f32x16 c3 = __builtin_amdgcn_mfma_f32_32x32x16_bf16(af, bfr3, zero, 0, 0, 0);
        acc3 = accmin16(acc3, c3);
    }
    acc0 = fminf(acc0, __shfl_xor(acc0, 32, 64));
    acc1 = fminf(acc1, __shfl_xor(acc1, 32, 64));
    acc2 = fminf(acc2, __shfl_xor(acc2, 32, 64));
    acc3 = fminf(acc3, __shfl_xor(acc3, 32, 64));
    if (lane < 32) {
        outp[lane]      = fmaxf(acc0, 0.f);
        outp[32 + lane] = fmaxf(acc1, 0.f);
        outp[64 + lane] = fmaxf(acc2, 0.f);
        outp[96 + lane] = fmaxf(acc3, 0.f);
    }
}

__global__ __launch_bounds__(256, 4) void pair_col_kernel(
    const float* __restrict__ raw, const ushort* __restrict__ As,
    float* __restrict__ colpart)
{
    const int tid = threadIdx.x, w = tid >> 6, lane = tid & 63, half = lane >> 5;
    int idx = blockIdx.x;                        // [0,1024)
    const int b = idx >> 9; idx &= 511;
    const int ob = idx & 31, sl = idx >> 5;      // ob:[0,32) sl:[0,16)
    const int own0 = ob * 512 + w * 128;
    const float4* ownp = (const float4*)raw + (size_t)b * MM + own0;
    const ushort* Ap = As + (((size_t)(b * (NN / 32) + sl * NT)) << 9) + lane * 8;
    float* outp = colpart + ((size_t)sl * BB + b) * MM + own0;
    pair_body(ownp, Ap, outp, lane, half);
}

__global__ __launch_bounds__(256, 4) void pair_row_kernel(
    const float* __restrict__ sampled, const ushort* __restrict__ Ar,
    float* __restrict__ rowpart)
{
    const int tid = threadIdx.x, w = tid >> 6, lane = tid & 63, half = lane >> 5;
    int idx = blockIdx.x;                        // [0,1024)
    const int b = idx >> 9; idx &= 511;
    const int ob = idx & 7, sl = idx >> 3;       // ob:[0,8) sl:[0,64)
    const int own0 = ob * 512 + w * 128;
    const float4* ownp = (const float4*)sampled + (size_t)b * NN + own0;
    const ushort* Ap = Ar + (((size_t)(b * (MM / 32) + sl * NT)) << 9) + lane * 8;
    float* outp = rowpart + ((size_t)sl * BB + b) * NN + own0;
    pair_body(ownp, Ap, outp, lane, half);
}

__global__ __launch_bounds__(256) void reduce_kernel(
    const float* __restrict__ rowpart,
    const float* __restrict__ colpart,
    float* __restrict__ part,            // [128][3]
    unsigned* __restrict__ counter,
    float* __restrict__ out)
{
    const int k = blockIdx.x, b = k >> 6, s = k & 63;
    const int tid = threadIdx.x;
    const float INF = __uint_as_float(INFBITS);

    const int col = s * 256 + tid;
    float v = INF;
#pragma unroll 4
    for (int sl = 0; sl < CSL; ++sl)
        v = fminf(v, colpart[((size_t)sl * BB + b) * MM + col]);
    float sB = sqrtf(v);

    const int row = s * 64 + (tid & 63);
    const int jq  = tid >> 6;
    float wv2 = INF;
#pragma unroll 4
    for (int q = 0; q < RSL / 4; ++q)
        wv2 = fminf(wv2, rowpart[((size_t)(jq * (RSL / 4) + q) * BB + b) * NN + row]);
    __shared__ float rred[4][64];
    rred[jq][tid & 63] = wv2;
    __syncthreads();
    float sF = 0.f, mF = 0.f;
    if (tid < 64) {
        float rmn = fminf(fminf(rred[0][tid], rred[1][tid]),
                          fminf(rred[2][tid], rred[3][tid]));
        float d = sqrtf(rmn);
        sF = d; mF = d;
    }

    for (int m = 1; m < 64; m <<= 1) {
        sB += __shfl_xor(sB, m, 64);
        sF += __shfl_xor(sF, m, 64);
        mF = fmaxf(mF, __shfl_xor(mF, m, 64));
    }
    __shared__ float red[3][4];
    const int lane = tid & 63, wvi = tid >> 6;
    if (lane == 0) { red[0][wvi] = sB; red[1][wvi] = sF; red[2][wvi] = mF; }
    __syncthreads();

    __shared__ bool isLast;
    if (tid == 0) {
        part[k * 3 + 0] = red[0][0] + red[0][1] + red[0][2] + red[0][3];
        part[k * 3 + 1] = red[1][0] + red[1][1] + red[1][2] + red[1][3];
        part[k * 3 + 2] = fmaxf(fmaxf(red[2][0], red[2][1]),
                                fmaxf(red[2][2], red[2][3]));
        __threadfence();
        isLast = (atomicAdd(counter, 1u) == 127u);
    }
    __syncthreads();
    if (!isLast) return;

    __threadfence();
    volatile const float* vp = part;
    float fB = 0.f, fF = 0.f, fM = 0.f;
    if (tid < 128) {
        fB = vp[tid * 3 + 0]; fF = vp[tid * 3 + 1]; fM = vp[tid * 3 + 2];
    }
    for (int m = 1; m < 64; m <<= 1) {
        fB += __shfl_xor(fB, m, 64);
        fF += __shfl_xor(fF, m, 64);
        fM = fmaxf(fM, __shfl_xor(fM, m, 64));
    }
    __shared__ float fin[2][3];
    if (tid < 128 && (tid & 63) == 0) {
        fin[tid >> 6][0] = fB; fin[tid >> 6][1] = fF; fin[tid >> 6][2] = fM;
    }
    __syncthreads();
    if (tid == 0) {
        float l0 = 5.f * fin[0][0] / (float)MM + fin[0][1] / (float)NN + fin[0][2];
        float l1 = 5.f * fin[1][0] / (float)MM + fin[1][1] / (float)NN + fin[1][2];
        *out = 0.5f * (l0 + l1);
    }
}

extern "C" void kernel_launch(void* const* d_in, const int* in_sizes, int n_in,
                              void* d_out, int out_size, void* d_ws, size_t ws_size,
                              hipStream_t stream) {
    const float* sampled = (const float*)d_in[0];
    const float* raw     = (const float*)d_in[1];
    ushort* As     = (ushort*)d_ws;                          // BB*NN*32B = 256 KB
    ushort* Ar     = As + (size_t)BB * NN * 16;              // BB*MM*32B = 1 MB
    float* colpart = (float*)(Ar + (size_t)BB * MM * 16);    // CSL*BB*MM = 2 MB
    float* rowpart = colpart + (size_t)CSL * BB * MM;        // RSL*BB*NN = 2 MB
    float* part    = rowpart + (size_t)RSL * BB * NN;
    unsigned* counter = (unsigned*)(part + 3 * 128);
    float* out     = (float*)d_out;

    pack_kernel<<<(BB * (NN + MM)) / 256, 256, 0, stream>>>(sampled, raw, As, Ar, counter);
    pair_col_kernel<<<1024, 256, 0, stream>>>(raw, As, colpart);
    pair_row_kernel<<<1024, 256, 0, stream>>>(sampled, Ar, rowpart);
    reduce_kernel<<<128, 256, 0, stream>>>(rowpart, colpart, part, counter, out);
}